// Round 15
// baseline (246.990 us; speedup 1.0000x reference)
//
#include <hip/hip_runtime.h>
#include <cmath>

#define SEQ    2048
#define DMODEL 1024
#define NHEADS 16
#define DK     64
#define MROWS  4096   // B*S
#define PITCH  72     // flash K/Q LDS pitch (bf16 elems)
#define VPITCH 68     // flash V^T permuted LDS pitch

typedef __bf16 bf16x8 __attribute__((ext_vector_type(8)));
typedef float  f32x4  __attribute__((ext_vector_type(4)));
typedef short  s16x4  __attribute__((ext_vector_type(4)));

__device__ __forceinline__ unsigned short f2bf(float f) {
    union { float f; unsigned u; } v; v.f = f;
    unsigned r = v.u + 0x7fffu + ((v.u >> 16) & 1u);   // RNE
    return (unsigned short)(r >> 16);
}

__device__ __forceinline__ float bf2f(unsigned short u) {
    union { unsigned u; float f; } v; v.u = ((unsigned)u) << 16; return v.f;
}

__device__ __forceinline__ void async16(const unsigned short* g, unsigned short* l) {
    __builtin_amdgcn_global_load_lds(
        (const __attribute__((address_space(1))) unsigned int*)(g),
        (__attribute__((address_space(3))) unsigned int*)(l),
        16, 0, 0);
}

// ---------------------------------------------------------------------------
// fp32 -> bf16 conversion of x, Wq|Wk|Wv (packed), Wo
// ---------------------------------------------------------------------------
__global__ __launch_bounds__(256)
void convert_kernel(const float* __restrict__ x,
                    const float* __restrict__ wq, const float* __restrict__ wk,
                    const float* __restrict__ wv, const float* __restrict__ wo,
                    unsigned short* __restrict__ xb,
                    unsigned short* __restrict__ wqkvb,
                    unsigned short* __restrict__ wob)
{
    const unsigned e = (blockIdx.x * 256u + threadIdx.x) * 8u;
    const float* src; unsigned short* dst; unsigned off;
    if      (e < 4194304u) { src = x;  dst = xb;             off = e;            }
    else if (e < 5242880u) { src = wq; dst = wqkvb;          off = e - 4194304u; }
    else if (e < 6291456u) { src = wk; dst = wqkvb+1048576u; off = e - 5242880u; }
    else if (e < 7340032u) { src = wv; dst = wqkvb+2097152u; off = e - 6291456u; }
    else                   { src = wo; dst = wob;            off = e - 7340032u; }
    float4 a = *(const float4*)(src + off);
    float4 b = *(const float4*)(src + off + 4);
    ushort4 u0, u1;
    u0.x=f2bf(a.x); u0.y=f2bf(a.y); u0.z=f2bf(a.z); u0.w=f2bf(a.w);
    u1.x=f2bf(b.x); u1.y=f2bf(b.y); u1.z=f2bf(b.z); u1.w=f2bf(b.w);
    *(ushort4*)(dst + off)     = u0;
    *(ushort4*)(dst + off + 4) = u1;
}

// ---------------------------------------------------------------------------
// bf16 MFMA GEMM (unchanged from R13 — measured best config).
// TM=64, TN templated; BK=64 single-buffered; coalesced async16 + XOR-8 swizzle.
// QKV: 64x128, grid (24,64); O-proj: 64x64, grid (16,64). launch_bounds(256,6).
// ---------------------------------------------------------------------------
template<int TN, int NCOLS, int MODE>
__global__ __launch_bounds__(256, 6)
void gemm_mfma_bt(const unsigned short* __restrict__ A,
                  const unsigned short* __restrict__ B,
                  void* __restrict__ Yqk,
                  unsigned short* __restrict__ Yvt)
{
    constexpr int BINST = TN / 32;
    constexpr int NT    = TN / 32;

    __shared__ unsigned short As[64 * 64];
    __shared__ unsigned short Bs[TN * 64];

    const int t    = threadIdx.x;
    const int w    = t >> 6;
    const int lane = t & 63;
    const int lq   = lane >> 4;
    const int ln   = lane & 15;
    const int m0   = blockIdx.y * 64;
    const int n0   = blockIdx.x * TN;

    const int mrow0 = (w & 1) * 32;
    const int ncol0 = (w >> 1) * (TN / 2);

    const int srow  = w*8 + (lane >> 3);
    const int gslot = (lane & 7) ^ (lane >> 3);

    const unsigned short* gA[2]; unsigned short* lA[2];
    #pragma unroll
    for (int i = 0; i < 2; ++i) {
        gA[i] = A + (size_t)(m0 + i*32 + srow) * 1024 + gslot*8;
        lA[i] = As + (i*32 + w*8) * 64;
    }
    const unsigned short* gB[BINST]; unsigned short* lB[BINST];
    #pragma unroll
    for (int i = 0; i < BINST; ++i) {
        gB[i] = B + (size_t)(n0 + i*32 + srow) * 1024 + gslot*8;
        lB[i] = Bs + (i*32 + w*8) * 64;
    }

    f32x4 acc[2][NT];
    #pragma unroll
    for (int mt = 0; mt < 2; ++mt)
        #pragma unroll
        for (int nt = 0; nt < NT; ++nt)
            #pragma unroll
            for (int r = 0; r < 4; ++r) acc[mt][nt][r] = 0.0f;

    const int fsw = (ln & 7);

    for (int k0 = 0; k0 < 1024; k0 += 64) {
        __syncthreads();
        #pragma unroll
        for (int i = 0; i < 2;     ++i) async16(gA[i] + k0, lA[i]);
        #pragma unroll
        for (int i = 0; i < BINST; ++i) async16(gB[i] + k0, lB[i]);
        __syncthreads();
        #pragma unroll
        for (int kh = 0; kh < 2; ++kh) {
            const int g  = kh*4 + lq;
            const int ps = (g ^ fsw) * 8;
            bf16x8 af[2], bf[NT];
            #pragma unroll
            for (int mt = 0; mt < 2; ++mt)
                af[mt] = *(const bf16x8*)&As[(mrow0 + mt*16 + ln)*64 + ps];
            #pragma unroll
            for (int nt = 0; nt < NT; ++nt)
                bf[nt] = *(const bf16x8*)&Bs[(ncol0 + nt*16 + ln)*64 + ps];
            #pragma unroll
            for (int mt = 0; mt < 2; ++mt)
                #pragma unroll
                for (int nt = 0; nt < NT; ++nt)
                    acc[mt][nt] = __builtin_amdgcn_mfma_f32_16x16x32_bf16(
                                      af[mt], bf[nt], acc[mt][nt], 0, 0, 0);
        }
    }

    if (MODE == 0) {
        float* Yf = (float*)Yqk;
        #pragma unroll
        for (int nt = 0; nt < NT; ++nt) {
            const int col = n0 + ncol0 + nt*16 + ln;
            #pragma unroll
            for (int mt = 0; mt < 2; ++mt) {
                const int row0 = m0 + mrow0 + mt*16 + lq*4;
                #pragma unroll
                for (int r = 0; r < 4; ++r)
                    Yf[(size_t)(row0 + r) * NCOLS + col] = acc[mt][nt][r];
            }
        }
    } else if (n0 < 2048) {
        unsigned short* Yb = (unsigned short*)Yqk;
        const float LOG_T = 9.210340371976184f / 32.0f;
        #pragma unroll
        for (int nt = 0; nt < NT; ++nt) {
            const int col = n0 + ncol0 + nt*16 + ln;
            const float fr = __expf(-(float)((col & 63) >> 1) * LOG_T);
            #pragma unroll
            for (int mt = 0; mt < 2; ++mt) {
                const int row0 = m0 + mrow0 + mt*16 + lq*4;
                #pragma unroll
                for (int r = 0; r < 4; ++r) {
                    const float v = acc[mt][nt][r];
                    float sn, cs;
                    __sincosf((float)((row0 + r) & (SEQ - 1)) * fr, &sn, &cs);
                    const float p = __shfl_xor(v, 1);
                    const float outv = ((ln & 1) == 0) ? (v*cs - p*sn) : (p*sn + v*cs);
                    Yb[(size_t)(row0 + r) * 2048 + col] = f2bf(outv);
                }
            }
        }
    } else {
        #pragma unroll
        for (int nt = 0; nt < NT; ++nt) {
            const int d = (n0 - 2048) + ncol0 + nt*16 + ln;
            #pragma unroll
            for (int mt = 0; mt < 2; ++mt) {
                const int row0 = m0 + mrow0 + mt*16 + lq*4;
                const int b = row0 >> 11;
                const int s = row0 & 2047;
                ushort4 o;
                o.x = f2bf(acc[mt][nt][0]); o.y = f2bf(acc[mt][nt][1]);
                o.z = f2bf(acc[mt][nt][2]); o.w = f2bf(acc[mt][nt][3]);
                *(ushort4*)&Yvt[((size_t)b*1024 + d) * 2048 + s] = o;
            }
        }
    }
}

// ---------------------------------------------------------------------------
// SPLIT-K MFMA flash attention (key-parity split). R14 PM: flash needs cheap
// tiles AND many waves — 64-q blocks (lean: ~56 VGPR, 17.9 KB) with each
// (b,h,qb) split over 2 blocks by key-tile parity -> 2048 blocks = 8/CU.
// Max-free softmax makes partials DIRECTLY ADDABLE (no max merge, no alpha):
// each split stores unnormalized O^T (bf16) + partial l (fp32); merge kernel
// normalizes. Total tile-visits unchanged; wave-parallelism 4x.
// ---------------------------------------------------------------------------
__global__ __launch_bounds__(256, 8)
void flash_split_kernel(const unsigned short* __restrict__ QK,
                        const unsigned short* __restrict__ Vtg,
                        unsigned short* __restrict__ Op0,
                        unsigned short* __restrict__ Op1,
                        float* __restrict__ Lp)
{
    __shared__ unsigned short Kt[64 * PITCH];    // Q stage / K tile
    __shared__ unsigned short Vt[64 * VPITCH];   // V^T tile, permuted layout

    const int t     = threadIdx.x;
    const int w     = t >> 6;
    const int lane  = t & 63;
    const int lq    = lane >> 4;
    const int ln    = lane & 15;
    const int bh    = blockIdx.x;
    const int iy    = blockIdx.y;               // 0..63
    const int split = iy & 1;
    const int qb    = 31 - (iy >> 1);           // heavy first
    const int b     = bh >> 4;
    const int h     = bh & 15;

    const unsigned short* Qg = QK + h*DK;                        // LD 2048
    const unsigned short* Kg = QK + 1024 + h*DK;                 // LD 2048
    const unsigned short* Vg = Vtg + ((size_t)b*1024 + h*DK) * 2048;  // [d][s]

    const int sr = t >> 2;            // staging row 0..63
    const int sc = (t & 3) * 16;      // staging col 0,16,32,48
    const int ks = t & 3;             // key-subtile for V staging

    const float SCALE2 = 0.125f * 1.4426950408889634f;   // 1/sqrt(dk) * log2e

    {   // stage Q tile -> Kt
        const unsigned short* qp = Qg + (size_t)(b*SEQ + qb*64 + sr) * 2048 + sc;
        *(float4*)&Kt[sr*PITCH + sc]     = *(const float4*)qp;
        *(float4*)&Kt[sr*PITCH + sc + 8] = *(const float4*)(qp + 8);
    }
    float4 kA, kB, vA, vB;
    {   // preload this split's first tile (index = split; always in-bounds)
        const unsigned short* kp = Kg + (size_t)(b*SEQ + split*64 + sr) * 2048 + sc;
        kA = *(const float4*)kp;  kB = *(const float4*)(kp + 8);
        const unsigned short* vp = Vg + (size_t)sr * 2048 + split*64 + sc;
        vA = *(const float4*)vp;  vB = *(const float4*)(vp + 8);
    }
    __syncthreads();
    const bf16x8 qf0 = *(const bf16x8*)&Kt[(w*16 + ln)*PITCH + lq*8];
    const bf16x8 qf1 = *(const bf16x8*)&Kt[(w*16 + ln)*PITCH + 32 + lq*8];

    f32x4 oacc[4];
    #pragma unroll
    for (int dt = 0; dt < 4; ++dt)
        #pragma unroll
        for (int r = 0; r < 4; ++r) oacc[dt][r] = 0.0f;
    float l_r = 0.0f;
    const int qg = qb*64 + w*16 + ln;

    for (int kt = split; kt <= qb; kt += 2) {
        __syncthreads();                    // qf/prev reads done
        *(float4*)&Kt[sr*PITCH + sc]     = kA;
        *(float4*)&Kt[sr*PITCH + sc + 8] = kB;
        {   // permuted V^T staging: 4 ds_write_b64
            const ushort4* va4 = (const ushort4*)&vA;
            const ushort4* vb4 = (const ushort4*)&vB;
            unsigned short* vbase = &Vt[sr*VPITCH + ks*4];
            *(ushort4*)(vbase +  0) = va4[0];
            *(ushort4*)(vbase + 16) = va4[1];
            *(ushort4*)(vbase + 32) = vb4[0];
            *(ushort4*)(vbase + 48) = vb4[1];
        }
        __syncthreads();                    // tile visible

        if (kt + 2 <= qb) {                 // prefetch this split's next tile
            const unsigned short* kp = Kg + (size_t)(b*SEQ + (kt+2)*64 + sr) * 2048 + sc;
            kA = *(const float4*)kp;  kB = *(const float4*)(kp + 8);
            const unsigned short* vp = Vg + (size_t)sr * 2048 + (kt+2)*64 + sc;
            vA = *(const float4*)vp;  vB = *(const float4*)(vp + 8);
        }

        // --- S^T = K Q^T
        f32x4 sacc[4];
        #pragma unroll
        for (int nt = 0; nt < 4; ++nt) {
            #pragma unroll
            for (int r = 0; r < 4; ++r) sacc[nt][r] = 0.0f;
            bf16x8 kf0 = *(const bf16x8*)&Kt[(nt*16 + ln)*PITCH + lq*8];
            bf16x8 kf1 = *(const bf16x8*)&Kt[(nt*16 + ln)*PITCH + 32 + lq*8];
            sacc[nt] = __builtin_amdgcn_mfma_f32_16x16x32_bf16(kf0, qf0, sacc[nt], 0, 0, 0);
            sacc[nt] = __builtin_amdgcn_mfma_f32_16x16x32_bf16(kf1, qf1, sacc[nt], 0, 0, 0);
        }

        // --- max-free softmax: p = exp2(min(s*scale, 50)); no cross-lane
        float p[16];
        if (kt == qb) {                     // diag tile: causal mask
            #pragma unroll
            for (int nt = 0; nt < 4; ++nt)
                #pragma unroll
                for (int r = 0; r < 4; ++r) {
                    float s = fminf(sacc[nt][r] * SCALE2, 50.0f);
                    if (kt*64 + nt*16 + lq*4 + r > qg) s = -INFINITY;
                    p[nt*4 + r] = __builtin_amdgcn_exp2f(s);
                }
        } else {
            #pragma unroll
            for (int i = 0; i < 16; ++i) {
                const int nt = i >> 2, r = i & 3;
                p[i] = __builtin_amdgcn_exp2f(fminf(sacc[nt][r] * SCALE2, 50.0f));
            }
        }
        float sum = 0.0f;
        #pragma unroll
        for (int i = 0; i < 16; ++i) sum += p[i];
        l_r += sum;

        // --- pack P^T (round-half-up via +0x8000, pack with v_perm)
        s16x4 pf[4];
        #pragma unroll
        for (int kk = 0; kk < 4; ++kk) {
            union { float f; unsigned u; } c0, c1, c2, c3;
            c0.f = p[kk*4+0]; c1.f = p[kk*4+1]; c2.f = p[kk*4+2]; c3.f = p[kk*4+3];
            unsigned lo = __builtin_amdgcn_perm(c1.u + 0x8000u, c0.u + 0x8000u, 0x07060302u);
            unsigned hi = __builtin_amdgcn_perm(c3.u + 0x8000u, c2.u + 0x8000u, 0x07060302u);
            union { unsigned u2[2]; s16x4 v; } pk;
            pk.u2[0] = lo; pk.u2[1] = hi;
            pf[kk] = pk.v;
        }

        // --- O^T += V^T P^T  (V-frags: 2 b128 per dt, permuted layout)
        #pragma unroll
        for (int dt = 0; dt < 4; ++dt) {
            union { bf16x8 v8; s16x4 h[2]; } u01, u23;
            u01.v8 = *(const bf16x8*)&Vt[(dt*16 + ln)*VPITCH + lq*16];
            u23.v8 = *(const bf16x8*)&Vt[(dt*16 + ln)*VPITCH + lq*16 + 8];
            oacc[dt] = __builtin_amdgcn_mfma_f32_16x16x16bf16_1k(u01.h[0], pf[0], oacc[dt], 0, 0, 0);
            oacc[dt] = __builtin_amdgcn_mfma_f32_16x16x16bf16_1k(u01.h[1], pf[1], oacc[dt], 0, 0, 0);
            oacc[dt] = __builtin_amdgcn_mfma_f32_16x16x16bf16_1k(u23.h[0], pf[2], oacc[dt], 0, 0, 0);
            oacc[dt] = __builtin_amdgcn_mfma_f32_16x16x16bf16_1k(u23.h[1], pf[3], oacc[dt], 0, 0, 0);
        }
    }

    // --- epilogue: store UNNORMALIZED partial O (bf16) + partial l (fp32).
    // Lane holds q = ln (fixed), d = dt*16 + lq*4 + r -> 4 contiguous d per
    // ushort4 at row q: direct global store, no LDS transpose, no barrier.
    l_r += __shfl_xor(l_r, 16);
    l_r += __shfl_xor(l_r, 32);
    unsigned short* Op = split ? Op1 : Op0;
    const size_t orow = ((size_t)b*2048 + qb*64 + w*16 + ln) * 1024 + h*64;
    #pragma unroll
    for (int dt = 0; dt < 4; ++dt) {
        ushort4 o;
        o.x = f2bf(oacc[dt][0]); o.y = f2bf(oacc[dt][1]);
        o.z = f2bf(oacc[dt][2]); o.w = f2bf(oacc[dt][3]);
        *(ushort4*)&Op[orow + dt*16 + lq*4] = o;
    }
    if (lq == 0)
        Lp[((size_t)(split*2 + b)*16 + h)*2048 + qb*64 + w*16 + ln] = l_r;
}

// ---------------------------------------------------------------------------
// Merge: ob[i] = (O0[i] + O1[i]) / (l0 + l1), in place over Op1 (=ob).
// Element-wise same-index -> in-place safe across blocks.
// ---------------------------------------------------------------------------
__global__ __launch_bounds__(256)
void merge_kernel(const unsigned short* __restrict__ Op0,
                  unsigned short* __restrict__ Op1ob,
                  const float* __restrict__ Lp)
{
    const unsigned e = (blockIdx.x * 256u + threadIdx.x) * 8u;   // < 4M
    const int row = e >> 10;
    const int col = e & 1023;
    const int b = row >> 11, q = row & 2047, h = col >> 6;
    const float l0 = Lp[((size_t)b*16 + h)*2048 + q];
    const float l1 = Lp[((size_t)(2 + b)*16 + h)*2048 + q];
    const float linv = 1.0f / (l0 + l1);
    ushort4 a0 = *(const ushort4*)(Op0 + e);
    ushort4 a1 = *(const ushort4*)(Op0 + e + 4);
    ushort4 b0 = *(const ushort4*)(Op1ob + e);
    ushort4 b1 = *(const ushort4*)(Op1ob + e + 4);
    ushort4 r0, r1;
    r0.x = f2bf((bf2f(a0.x) + bf2f(b0.x)) * linv);
    r0.y = f2bf((bf2f(a0.y) + bf2f(b0.y)) * linv);
    r0.z = f2bf((bf2f(a0.z) + bf2f(b0.z)) * linv);
    r0.w = f2bf((bf2f(a0.w) + bf2f(b0.w)) * linv);
    r1.x = f2bf((bf2f(a1.x) + bf2f(b1.x)) * linv);
    r1.y = f2bf((bf2f(a1.y) + bf2f(b1.y)) * linv);
    r1.z = f2bf((bf2f(a1.z) + bf2f(b1.z)) * linv);
    r1.w = f2bf((bf2f(a1.w) + bf2f(b1.w)) * linv);
    *(ushort4*)(Op1ob + e)     = r0;
    *(ushort4*)(Op1ob + e + 4) = r1;
}

// ---------------------------------------------------------------------------
extern "C" void kernel_launch(void* const* d_in, const int* in_sizes, int n_in,
                              void* d_out, int out_size, void* d_ws, size_t ws_size,
                              hipStream_t stream)
{
    const float* x  = (const float*)d_in[0];
    const float* Wq = (const float*)d_in[1];
    const float* Wk = (const float*)d_in[2];
    const float* Wv = (const float*)d_in[3];
    const float* Wo = (const float*)d_in[4];
    float* out = (float*)d_out;

    unsigned short* xb    = (unsigned short*)d_ws;   //  4M elems
    unsigned short* wqkvb = xb + 4194304;            //  3M
    unsigned short* wob   = wqkvb + 3145728;         //  1M
    unsigned short* qk    = wob + 1048576;           //  8M  [4096][2048]
    unsigned short* vt    = qk + 8388608;            //  4M  [2][1024][2048]
    unsigned short* ob    = vt + 4194304;            //  4M  [4096][1024]
    // total 24M elems = 48 MB.  Aliases (live only during/after flash):
    unsigned short* op0 = xb;            // split-0 partial O (xb dead post-QKV)
    unsigned short* op1 = ob;            // split-1 partial O; merged in place
    float*          lp  = (float*)wqkvb; // 131072 floats (wqkvb dead post-QKV)

    convert_kernel<<<4096, 256, 0, stream>>>(x, Wq, Wk, Wv, Wo, xb, wqkvb, wob);

    // QKV: 64x128 tiles, 1536 blocks (~6/CU)
    gemm_mfma_bt<128, 2048, 1><<<dim3(24, 64), 256, 0, stream>>>(xb, wqkvb, qk, vt);

    // flash split-K: 2048 blocks (8/CU), heavy q-tiles first
    flash_split_kernel<<<dim3(32, 64), 256, 0, stream>>>(qk, vt, op0, op1, lp);

    // merge partials -> ob (in place over op1)
    merge_kernel<<<2048, 256, 0, stream>>>(op0, op1, lp);

    // O-proj: 64x64 tiles, 1024 blocks (4/CU)
    gemm_mfma_bt<64, 1024, 0><<<dim3(16, 64), 256, 0, stream>>>(ob, wob, out, nullptr);
}

// Round 16
// 170.083 us; speedup vs baseline: 1.4522x; 1.4522x over previous
//
#include <hip/hip_runtime.h>
#include <cmath>

#define SEQ    2048
#define DMODEL 1024
#define NHEADS 16
#define DK     64
#define MROWS  4096   // B*S
#define PITCH  72     // flash K/Q LDS pitch (bf16 elems)
#define VPITCH 68     // flash V^T permuted LDS pitch

typedef __bf16 bf16x8 __attribute__((ext_vector_type(8)));
typedef float  f32x4  __attribute__((ext_vector_type(4)));
typedef short  s16x4  __attribute__((ext_vector_type(4)));

__device__ __forceinline__ unsigned short f2bf(float f) {
    union { float f; unsigned u; } v; v.f = f;
    unsigned r = v.u + 0x7fffu + ((v.u >> 16) & 1u);   // RNE
    return (unsigned short)(r >> 16);
}

__device__ __forceinline__ void async16(const unsigned short* g, unsigned short* l) {
    __builtin_amdgcn_global_load_lds(
        (const __attribute__((address_space(1))) unsigned int*)(g),
        (__attribute__((address_space(3))) unsigned int*)(l),
        16, 0, 0);
}

// ---------------------------------------------------------------------------
// fp32 -> bf16 conversion of x, Wq|Wk|Wv (packed), Wo
// ---------------------------------------------------------------------------
__global__ __launch_bounds__(256)
void convert_kernel(const float* __restrict__ x,
                    const float* __restrict__ wq, const float* __restrict__ wk,
                    const float* __restrict__ wv, const float* __restrict__ wo,
                    unsigned short* __restrict__ xb,
                    unsigned short* __restrict__ wqkvb,
                    unsigned short* __restrict__ wob)
{
    const unsigned e = (blockIdx.x * 256u + threadIdx.x) * 8u;
    const float* src; unsigned short* dst; unsigned off;
    if      (e < 4194304u) { src = x;  dst = xb;             off = e;            }
    else if (e < 5242880u) { src = wq; dst = wqkvb;          off = e - 4194304u; }
    else if (e < 6291456u) { src = wk; dst = wqkvb+1048576u; off = e - 5242880u; }
    else if (e < 7340032u) { src = wv; dst = wqkvb+2097152u; off = e - 6291456u; }
    else                   { src = wo; dst = wob;            off = e - 7340032u; }
    float4 a = *(const float4*)(src + off);
    float4 b = *(const float4*)(src + off + 4);
    ushort4 u0, u1;
    u0.x=f2bf(a.x); u0.y=f2bf(a.y); u0.z=f2bf(a.z); u0.w=f2bf(a.w);
    u1.x=f2bf(b.x); u1.y=f2bf(b.y); u1.z=f2bf(b.z); u1.w=f2bf(b.w);
    *(ushort4*)(dst + off)     = u0;
    *(ushort4*)(dst + off + 4) = u1;
}

// ---------------------------------------------------------------------------
// bf16 MFMA GEMM (unchanged from R13 — measured best config).
// TM=64, TN templated; BK=64 single-buffered; coalesced async16 + XOR-8 swizzle.
// QKV: 64x128, grid (24,64); O-proj: 64x64, grid (16,64). launch_bounds(256,6).
// ---------------------------------------------------------------------------
template<int TN, int NCOLS, int MODE>
__global__ __launch_bounds__(256, 6)
void gemm_mfma_bt(const unsigned short* __restrict__ A,
                  const unsigned short* __restrict__ B,
                  void* __restrict__ Yqk,
                  unsigned short* __restrict__ Yvt)
{
    constexpr int BINST = TN / 32;
    constexpr int NT    = TN / 32;

    __shared__ unsigned short As[64 * 64];
    __shared__ unsigned short Bs[TN * 64];

    const int t    = threadIdx.x;
    const int w    = t >> 6;
    const int lane = t & 63;
    const int lq   = lane >> 4;
    const int ln   = lane & 15;
    const int m0   = blockIdx.y * 64;
    const int n0   = blockIdx.x * TN;

    const int mrow0 = (w & 1) * 32;
    const int ncol0 = (w >> 1) * (TN / 2);

    const int srow  = w*8 + (lane >> 3);
    const int gslot = (lane & 7) ^ (lane >> 3);

    const unsigned short* gA[2]; unsigned short* lA[2];
    #pragma unroll
    for (int i = 0; i < 2; ++i) {
        gA[i] = A + (size_t)(m0 + i*32 + srow) * 1024 + gslot*8;
        lA[i] = As + (i*32 + w*8) * 64;
    }
    const unsigned short* gB[BINST]; unsigned short* lB[BINST];
    #pragma unroll
    for (int i = 0; i < BINST; ++i) {
        gB[i] = B + (size_t)(n0 + i*32 + srow) * 1024 + gslot*8;
        lB[i] = Bs + (i*32 + w*8) * 64;
    }

    f32x4 acc[2][NT];
    #pragma unroll
    for (int mt = 0; mt < 2; ++mt)
        #pragma unroll
        for (int nt = 0; nt < NT; ++nt)
            #pragma unroll
            for (int r = 0; r < 4; ++r) acc[mt][nt][r] = 0.0f;

    const int fsw = (ln & 7);

    for (int k0 = 0; k0 < 1024; k0 += 64) {
        __syncthreads();
        #pragma unroll
        for (int i = 0; i < 2;     ++i) async16(gA[i] + k0, lA[i]);
        #pragma unroll
        for (int i = 0; i < BINST; ++i) async16(gB[i] + k0, lB[i]);
        __syncthreads();
        #pragma unroll
        for (int kh = 0; kh < 2; ++kh) {
            const int g  = kh*4 + lq;
            const int ps = (g ^ fsw) * 8;
            bf16x8 af[2], bf[NT];
            #pragma unroll
            for (int mt = 0; mt < 2; ++mt)
                af[mt] = *(const bf16x8*)&As[(mrow0 + mt*16 + ln)*64 + ps];
            #pragma unroll
            for (int nt = 0; nt < NT; ++nt)
                bf[nt] = *(const bf16x8*)&Bs[(ncol0 + nt*16 + ln)*64 + ps];
            #pragma unroll
            for (int mt = 0; mt < 2; ++mt)
                #pragma unroll
                for (int nt = 0; nt < NT; ++nt)
                    acc[mt][nt] = __builtin_amdgcn_mfma_f32_16x16x32_bf16(
                                      af[mt], bf[nt], acc[mt][nt], 0, 0, 0);
        }
    }

    if (MODE == 0) {
        float* Yf = (float*)Yqk;
        #pragma unroll
        for (int nt = 0; nt < NT; ++nt) {
            const int col = n0 + ncol0 + nt*16 + ln;
            #pragma unroll
            for (int mt = 0; mt < 2; ++mt) {
                const int row0 = m0 + mrow0 + mt*16 + lq*4;
                #pragma unroll
                for (int r = 0; r < 4; ++r)
                    Yf[(size_t)(row0 + r) * NCOLS + col] = acc[mt][nt][r];
            }
        }
    } else if (n0 < 2048) {
        unsigned short* Yb = (unsigned short*)Yqk;
        const float LOG_T = 9.210340371976184f / 32.0f;
        #pragma unroll
        for (int nt = 0; nt < NT; ++nt) {
            const int col = n0 + ncol0 + nt*16 + ln;
            const float fr = __expf(-(float)((col & 63) >> 1) * LOG_T);
            #pragma unroll
            for (int mt = 0; mt < 2; ++mt) {
                const int row0 = m0 + mrow0 + mt*16 + lq*4;
                #pragma unroll
                for (int r = 0; r < 4; ++r) {
                    const float v = acc[mt][nt][r];
                    float sn, cs;
                    __sincosf((float)((row0 + r) & (SEQ - 1)) * fr, &sn, &cs);
                    const float p = __shfl_xor(v, 1);
                    const float outv = ((ln & 1) == 0) ? (v*cs - p*sn) : (p*sn + v*cs);
                    Yb[(size_t)(row0 + r) * 2048 + col] = f2bf(outv);
                }
            }
        }
    } else {
        #pragma unroll
        for (int nt = 0; nt < NT; ++nt) {
            const int d = (n0 - 2048) + ncol0 + nt*16 + ln;
            #pragma unroll
            for (int mt = 0; mt < 2; ++mt) {
                const int row0 = m0 + mrow0 + mt*16 + lq*4;
                const int b = row0 >> 11;
                const int s = row0 & 2047;
                ushort4 o;
                o.x = f2bf(acc[mt][nt][0]); o.y = f2bf(acc[mt][nt][1]);
                o.z = f2bf(acc[mt][nt][2]); o.w = f2bf(acc[mt][nt][3]);
                *(ushort4*)&Yvt[((size_t)b*1024 + d) * 2048 + s] = o;
            }
        }
    }
}

// ---------------------------------------------------------------------------
// MFMA flash attention, R13 structure (64-q blocks, grid 1024, no launch
// bounds cap — R15 PM: capping VGPR to fit 8 blocks/CU caused a spill cliff,
// FETCH 12->120 MB) + DOUBLE-BUFFERED K/V tiles: ONE barrier per key-tile
// instead of two. LDS 17.9 -> 35.8 KB keeps 4 blocks/CU (grid-limited at 4
// anyway — no occupancy cost, unlike the R11 GEMM dbuf failure).
// Single-barrier correctness: the barrier after writing buf[k&1] orders all
// waves' iter-(k-1) reads of buf[(k-1)&1] before any iter-(k+1) write to it.
// Transposed-P, max-free softmax, permuted-V LDS as before.
// ---------------------------------------------------------------------------
__global__ __launch_bounds__(256)
void flash_mfma_kernel(const unsigned short* __restrict__ QK,
                       const unsigned short* __restrict__ Vtg,
                       unsigned short* __restrict__ Ob)
{
    __shared__ unsigned short Kt[2][64 * PITCH];   // K tiles (buf 0 also stages Q / O)
    __shared__ unsigned short Vt[2][64 * VPITCH];  // V^T tiles, permuted layout

    const int t    = threadIdx.x;
    const int w    = t >> 6;
    const int lane = t & 63;
    const int lq   = lane >> 4;
    const int ln   = lane & 15;
    const int bh   = blockIdx.x;
    const int qb   = 31 - (int)blockIdx.y;      // heavy first
    const int b    = bh >> 4;
    const int h    = bh & 15;

    const unsigned short* Qg = QK + h*DK;                        // LD 2048
    const unsigned short* Kg = QK + 1024 + h*DK;                 // LD 2048
    const unsigned short* Vg = Vtg + ((size_t)b*1024 + h*DK) * 2048;  // [d][s]

    const int sr = t >> 2;            // staging row 0..63
    const int sc = (t & 3) * 16;      // staging col 0,16,32,48
    const int ks = t & 3;             // key-subtile for V staging

    const float SCALE2 = 0.125f * 1.4426950408889634f;   // 1/sqrt(dk) * log2e

    {   // stage Q tile -> Kt[0]
        const unsigned short* qp = Qg + (size_t)(b*SEQ + qb*64 + sr) * 2048 + sc;
        *(float4*)&Kt[0][sr*PITCH + sc]     = *(const float4*)qp;
        *(float4*)&Kt[0][sr*PITCH + sc + 8] = *(const float4*)(qp + 8);
    }
    float4 kA, kB, vA, vB;
    {   // preload K/V^T tile 0 into registers
        const unsigned short* kp = Kg + (size_t)(b*SEQ + sr) * 2048 + sc;
        kA = *(const float4*)kp;  kB = *(const float4*)(kp + 8);
        const unsigned short* vp = Vg + (size_t)sr * 2048 + sc;
        vA = *(const float4*)vp;  vB = *(const float4*)(vp + 8);
    }
    __syncthreads();
    const bf16x8 qf0 = *(const bf16x8*)&Kt[0][(w*16 + ln)*PITCH + lq*8];
    const bf16x8 qf1 = *(const bf16x8*)&Kt[0][(w*16 + ln)*PITCH + 32 + lq*8];
    __syncthreads();                        // qf reads done before kt=0 writes Kt[0]

    f32x4 oacc[4];
    #pragma unroll
    for (int dt = 0; dt < 4; ++dt)
        #pragma unroll
        for (int r = 0; r < 4; ++r) oacc[dt][r] = 0.0f;
    float l_r = 0.0f;
    const int qg = qb*64 + w*16 + ln;

    for (int kt = 0; kt <= qb; ++kt) {
        const int buf = kt & 1;
        // write this tile's buffer (its last readers finished at kt-2,
        // ordered by the kt-1 barrier)
        *(float4*)&Kt[buf][sr*PITCH + sc]     = kA;
        *(float4*)&Kt[buf][sr*PITCH + sc + 8] = kB;
        {   // permuted V^T staging: 4 ds_write_b64
            const ushort4* va4 = (const ushort4*)&vA;
            const ushort4* vb4 = (const ushort4*)&vB;
            unsigned short* vbase = &Vt[buf][sr*VPITCH + ks*4];
            *(ushort4*)(vbase +  0) = va4[0];
            *(ushort4*)(vbase + 16) = va4[1];
            *(ushort4*)(vbase + 32) = vb4[0];
            *(ushort4*)(vbase + 48) = vb4[1];
        }
        __syncthreads();                    // the ONE barrier per tile

        if (kt < qb) {                      // prefetch next tile
            const unsigned short* kp = Kg + (size_t)(b*SEQ + (kt+1)*64 + sr) * 2048 + sc;
            kA = *(const float4*)kp;  kB = *(const float4*)(kp + 8);
            const unsigned short* vp = Vg + (size_t)sr * 2048 + (kt+1)*64 + sc;
            vA = *(const float4*)vp;  vB = *(const float4*)(vp + 8);
        }

        // --- S^T = K Q^T
        f32x4 sacc[4];
        #pragma unroll
        for (int nt = 0; nt < 4; ++nt) {
            #pragma unroll
            for (int r = 0; r < 4; ++r) sacc[nt][r] = 0.0f;
            bf16x8 kf0 = *(const bf16x8*)&Kt[buf][(nt*16 + ln)*PITCH + lq*8];
            bf16x8 kf1 = *(const bf16x8*)&Kt[buf][(nt*16 + ln)*PITCH + 32 + lq*8];
            sacc[nt] = __builtin_amdgcn_mfma_f32_16x16x32_bf16(kf0, qf0, sacc[nt], 0, 0, 0);
            sacc[nt] = __builtin_amdgcn_mfma_f32_16x16x32_bf16(kf1, qf1, sacc[nt], 0, 0, 0);
        }

        // --- max-free softmax: p = exp2(min(s*scale, 50)); no cross-lane
        float p[16];
        if (kt == qb) {                     // diag tile: causal mask
            #pragma unroll
            for (int nt = 0; nt < 4; ++nt)
                #pragma unroll
                for (int r = 0; r < 4; ++r) {
                    float s = fminf(sacc[nt][r] * SCALE2, 50.0f);
                    if (kt*64 + nt*16 + lq*4 + r > qg) s = -INFINITY;
                    p[nt*4 + r] = __builtin_amdgcn_exp2f(s);
                }
        } else {
            #pragma unroll
            for (int i = 0; i < 16; ++i) {
                const int nt = i >> 2, r = i & 3;
                p[i] = __builtin_amdgcn_exp2f(fminf(sacc[nt][r] * SCALE2, 50.0f));
            }
        }
        float sum = 0.0f;
        #pragma unroll
        for (int i = 0; i < 16; ++i) sum += p[i];
        l_r += sum;

        // --- pack P^T (round-half-up via +0x8000, pack with v_perm)
        s16x4 pf[4];
        #pragma unroll
        for (int kk = 0; kk < 4; ++kk) {
            union { float f; unsigned u; } c0, c1, c2, c3;
            c0.f = p[kk*4+0]; c1.f = p[kk*4+1]; c2.f = p[kk*4+2]; c3.f = p[kk*4+3];
            unsigned lo = __builtin_amdgcn_perm(c1.u + 0x8000u, c0.u + 0x8000u, 0x07060302u);
            unsigned hi = __builtin_amdgcn_perm(c3.u + 0x8000u, c2.u + 0x8000u, 0x07060302u);
            union { unsigned u2[2]; s16x4 v; } pk;
            pk.u2[0] = lo; pk.u2[1] = hi;
            pf[kk] = pk.v;
        }

        // --- O^T += V^T P^T  (V-frags: 2 b128 per dt, permuted layout)
        #pragma unroll
        for (int dt = 0; dt < 4; ++dt) {
            union { bf16x8 v8; s16x4 h[2]; } u01, u23;
            u01.v8 = *(const bf16x8*)&Vt[buf][(dt*16 + ln)*VPITCH + lq*16];
            u23.v8 = *(const bf16x8*)&Vt[buf][(dt*16 + ln)*VPITCH + lq*16 + 8];
            oacc[dt] = __builtin_amdgcn_mfma_f32_16x16x16bf16_1k(u01.h[0], pf[0], oacc[dt], 0, 0, 0);
            oacc[dt] = __builtin_amdgcn_mfma_f32_16x16x16bf16_1k(u01.h[1], pf[1], oacc[dt], 0, 0, 0);
            oacc[dt] = __builtin_amdgcn_mfma_f32_16x16x16bf16_1k(u23.h[0], pf[2], oacc[dt], 0, 0, 0);
            oacc[dt] = __builtin_amdgcn_mfma_f32_16x16x16bf16_1k(u23.h[1], pf[3], oacc[dt], 0, 0, 0);
        }
    }

    // --- epilogue: reduce l across quads, normalize, transpose via Kt[0], store
    l_r += __shfl_xor(l_r, 16);
    l_r += __shfl_xor(l_r, 32);
    const float linv = 1.0f / l_r;
    __syncthreads();                        // last tile reads done
    #pragma unroll
    for (int dt = 0; dt < 4; ++dt)
        #pragma unroll
        for (int r = 0; r < 4; ++r)
            Kt[0][(w*16 + ln)*PITCH + dt*16 + lq*4 + r] = f2bf(oacc[dt][r] * linv);
    __syncthreads();
    {
        unsigned short* op = Ob + (size_t)(b*SEQ + qb*64 + sr) * DMODEL + h*DK + sc;
        *(float4*)(op)     = *(const float4*)&Kt[0][sr*PITCH + sc];
        *(float4*)(op + 8) = *(const float4*)&Kt[0][sr*PITCH + sc + 8];
    }
}

// ---------------------------------------------------------------------------
extern "C" void kernel_launch(void* const* d_in, const int* in_sizes, int n_in,
                              void* d_out, int out_size, void* d_ws, size_t ws_size,
                              hipStream_t stream)
{
    const float* x  = (const float*)d_in[0];
    const float* Wq = (const float*)d_in[1];
    const float* Wk = (const float*)d_in[2];
    const float* Wv = (const float*)d_in[3];
    const float* Wo = (const float*)d_in[4];
    float* out = (float*)d_out;

    unsigned short* xb    = (unsigned short*)d_ws;   //  4M elems
    unsigned short* wqkvb = xb + 4194304;            //  3M
    unsigned short* wob   = wqkvb + 3145728;         //  1M
    unsigned short* qk    = wob + 1048576;           //  8M  [4096][2048]
    unsigned short* vt    = qk + 8388608;            //  4M  [2][1024][2048]
    unsigned short* ob    = vt + 4194304;            //  4M  [4096][1024]
    // total 24M elems = 48 MB

    convert_kernel<<<4096, 256, 0, stream>>>(x, Wq, Wk, Wv, Wo, xb, wqkvb, wob);

    // QKV: 64x128 tiles, 1536 blocks (~6/CU)
    gemm_mfma_bt<128, 2048, 1><<<dim3(24, 64), 256, 0, stream>>>(xb, wqkvb, qk, vt);

    // flash: 64-q blocks, grid (32,32)=1024, dbuf single-barrier
    flash_mfma_kernel<<<dim3(32, 32), 256, 0, stream>>>(qk, vt, ob);

    // O-proj: 64x64 tiles, 1024 blocks (4/CU)
    gemm_mfma_bt<64, 1024, 0><<<dim3(16, 64), 256, 0, stream>>>(ob, wob, out, nullptr);
}